// Round 7
// baseline (276.025 us; speedup 1.0000x reference)
//
#include <hip/hip_runtime.h>
#include <hip/hip_bf16.h>

#define NN 10000
#define NE 160000
#define NH 32
#define LRELU_SLOPE 0.2f
#define SM_EPS 1e-16f
#define SM_SHIFT 16.0f

typedef __hip_bfloat16 bf16;
typedef __attribute__((ext_vector_type(8))) __bf16 bf16x8;
typedef __attribute__((ext_vector_type(4))) float f32x4;

__device__ __forceinline__ float asf(unsigned int u) {
    union { unsigned int u; float f; } v; v.u = u; return v.f;
}

// ---------------- detect edge dtype + zero deg ----------------
__global__ void k_detect_zero(const unsigned int* __restrict__ raw, int* __restrict__ flag,
                              int* __restrict__ deg) {
    int i = blockIdx.x * blockDim.x + threadIdx.x;
    if (i < NN) deg[i] = 0;
    if (i == 0) {
        int z = 1;
        for (int j = 1; j < 32; j += 2) z &= (raw[j] == 0u);
        *flag = z;   // 1 => int64
    }
}
// ---------------- normalize edges + histogram ----------------
__global__ void k_norm_hist(const int* __restrict__ raw, const int* __restrict__ flag,
                            int* __restrict__ srcv, int* __restrict__ dstv, int* __restrict__ deg) {
    int e = blockIdx.x * blockDim.x + threadIdx.x;
    if (e >= NE) return;
    int s, d;
    if (*flag) { s = raw[2 * e]; d = raw[2 * (NE + e)]; }
    else       { s = raw[e];     d = raw[NE + e]; }
    srcv[e] = s; dstv[e] = d;
    atomicAdd(&deg[d], 1);
}
// shfl-based scan, 1024 threads, 10 chunks
__global__ void k_scan(const int* __restrict__ deg, int* __restrict__ offs, int* __restrict__ cursor) {
    __shared__ int wsum[16], wpre[16];
    __shared__ int base;
    const int tid = threadIdx.x, lane = tid & 63, wid = tid >> 6;
    if (tid == 0) base = 0;
    __syncthreads();
    for (int chunk = 0; chunk < NN; chunk += 1024) {
        int idx = chunk + tid;
        int v = (idx < NN) ? deg[idx] : 0;
        int s = v;
        #pragma unroll
        for (int off = 1; off < 64; off <<= 1) {
            int t = __shfl_up(s, off);
            if (lane >= off) s += t;
        }
        if (lane == 63) wsum[wid] = s;
        __syncthreads();
        if (wid == 0) {
            int ws = (lane < 16) ? wsum[lane] : 0;
            #pragma unroll
            for (int off = 1; off < 16; off <<= 1) {
                int t = __shfl_up(ws, off);
                if (lane >= off) ws += t;
            }
            if (lane < 16) wpre[lane] = ws;
        }
        __syncthreads();
        int wbase = (wid == 0) ? 0 : wpre[wid - 1];
        int excl = base + wbase + s - v;
        if (idx < NN) { offs[idx] = excl; cursor[idx] = excl; }
        int total = wpre[15];
        __syncthreads();
        if (tid == 0) base += total;
        __syncthreads();
    }
    if (tid == 0) offs[NN] = base;
}
__global__ void k_scatter(const int* __restrict__ srcv, const int* __restrict__ dstv,
                          int* __restrict__ cursor, int* __restrict__ srcs) {
    int e = blockIdx.x * blockDim.x + threadIdx.x;
    if (e < NE) {
        int p = atomicAdd(&cursor[dstv[e]], 1);
        srcs[p] = srcv[e];
    }
}

// ---------------- fused prep: cast X, transpose W1, transpose W2 ----------------
__global__ void k_prep(const float* __restrict__ X, bf16* __restrict__ Xb,
                       const float* __restrict__ W1, bf16* __restrict__ Wt1,
                       const float* __restrict__ W2, bf16* __restrict__ Wt2) {
    int i = blockIdx.x * blockDim.x + threadIdx.x;
    if (i < NN * 128) { Xb[i] = __float2bfloat16(X[i]); return; }
    i -= NN * 128;
    if (i < 128 * 2048) {
        int k = i / 2048, m = i - k * 2048;
        Wt1[(size_t)m * 128 + k] = __float2bfloat16(W1[i]);
        return;
    }
    i -= 128 * 2048;
    if (i < 64 * 1024) {
        int k = i / 1024, m = i - k * 1024;
        Wt2[(size_t)m * 64 + k] = __float2bfloat16(W2[i]);
    }
}

// ------- MFMA GEMM: XPB[n, M](bf16) = Xb[n, :K] @ Wt^T; fused alpha dots -------
template<int K, int M, int C>
__global__ __launch_bounds__(256) void k_gemm_mfma(
        const bf16* __restrict__ Xb, const bf16* __restrict__ Wt,
        const float* __restrict__ Asrc, const float* __restrict__ Adst,
        bf16* __restrict__ XPB, float* __restrict__ aS, float* __restrict__ aD) {
    constexpr int BM = 64, BN = 128;
    constexpr int KB = K * 2;            // LDS row bytes
    constexpr int NHB = BN / C;          // heads per block (2 or 4)
    constexpr int WPH = C / 32;          // waves per head  (2 or 1)
    __shared__ char lds[(BM + BN) * KB];
    __shared__ float sredS[4][BM], sredD[4][BM];
    char* lA = lds;
    char* lB = lds + BM * KB;

    const int tid = threadIdx.x;
    const int wv = tid >> 6, ln = tid & 63;
    const int lrow = ln & 15, lkb = ln >> 4;
    const int brow = blockIdx.x * BM;
    const int bcol = blockIdx.y * BN;

    #pragma unroll
    for (int c = 0; c < BM * K / 8 / 256; c++) {
        int it = c * 256 + tid;
        int r = it / (K / 8), kc = (it % (K / 8)) * 8;
        int node = brow + r;
        uint4 v = make_uint4(0u, 0u, 0u, 0u);
        if (node < NN) v = *reinterpret_cast<const uint4*>(&Xb[(size_t)node * K + kc]);
        *reinterpret_cast<uint4*>(lA + ((r * KB + kc * 2) ^ ((r & 7) << 4))) = v;
    }
    #pragma unroll
    for (int c = 0; c < BN * K / 8 / 256; c++) {
        int it = c * 256 + tid;
        int r = it / (K / 8), kc = (it % (K / 8)) * 8;
        uint4 v = *reinterpret_cast<const uint4*>(&Wt[(size_t)(bcol + r) * K + kc]);
        *reinterpret_cast<uint4*>(lB + ((r * KB + kc * 2) ^ ((r & 7) << 4))) = v;
    }
    __syncthreads();

    f32x4 acc[4][2];
    #pragma unroll
    for (int mi = 0; mi < 4; mi++)
        #pragma unroll
        for (int nj = 0; nj < 2; nj++) acc[mi][nj] = (f32x4){0.f, 0.f, 0.f, 0.f};

    #pragma unroll
    for (int ks = 0; ks < K / 32; ks++) {
        const int k0 = ks * 32 + lkb * 8;
        bf16x8 af[4], bfr[2];
        #pragma unroll
        for (int mi = 0; mi < 4; mi++) {
            int r = mi * 16 + lrow;
            af[mi] = *reinterpret_cast<const bf16x8*>(lA + ((r * KB + k0 * 2) ^ ((r & 7) << 4)));
        }
        #pragma unroll
        for (int nj = 0; nj < 2; nj++) {
            int r = wv * 32 + nj * 16 + lrow;
            bfr[nj] = *reinterpret_cast<const bf16x8*>(lB + ((r * KB + k0 * 2) ^ ((r & 7) << 4)));
        }
        #pragma unroll
        for (int mi = 0; mi < 4; mi++)
            #pragma unroll
            for (int nj = 0; nj < 2; nj++)
                acc[mi][nj] = __builtin_amdgcn_mfma_f32_16x16x32_bf16(af[mi], bfr[nj], acc[mi][nj], 0, 0, 0);
    }

    // epilogue: D col = lane&15, row = (lane>>4)*4 + reg  [m89]
    float ar0 = Asrc[bcol + wv * 32 + lrow];
    float ar1 = Asrc[bcol + wv * 32 + 16 + lrow];
    float ad0 = Adst[bcol + wv * 32 + lrow];
    float ad1 = Adst[bcol + wv * 32 + 16 + lrow];

    #pragma unroll
    for (int mi = 0; mi < 4; mi++) {
        #pragma unroll
        for (int r = 0; r < 4; r++) {
            int rowl = mi * 16 + lkb * 4 + r;
            int row = brow + rowl;
            if (row < NN) {
                XPB[(size_t)row * M + bcol + wv * 32 + lrow]      = __float2bfloat16(acc[mi][0][r]);
                XPB[(size_t)row * M + bcol + wv * 32 + 16 + lrow] = __float2bfloat16(acc[mi][1][r]);
            }
            float vs = acc[mi][0][r] * ar0 + acc[mi][1][r] * ar1;
            float vd = acc[mi][0][r] * ad0 + acc[mi][1][r] * ad1;
            vs += __shfl_xor(vs, 1); vd += __shfl_xor(vd, 1);
            vs += __shfl_xor(vs, 2); vd += __shfl_xor(vd, 2);
            vs += __shfl_xor(vs, 4); vd += __shfl_xor(vd, 4);
            vs += __shfl_xor(vs, 8); vd += __shfl_xor(vd, 8);
            if (lrow == 0) {
                sredS[wv][rowl] = vs;
                sredD[wv][rowl] = vd;
            }
        }
    }
    __syncthreads();
    if (tid < BM) {
        int node = brow + tid;
        if (node < NN) {
            #pragma unroll
            for (int hb = 0; hb < NHB; hb++) {
                float ss = 0.f, dd = 0.f;
                #pragma unroll
                for (int w = 0; w < WPH; w++) {
                    ss += sredS[hb * WPH + w][tid];
                    dd += sredD[hb * WPH + w][tid];
                }
                int h = bcol / C + hb;
                aS[node * NH + h] = ss;
                aD[node * NH + h] = dd;
            }
        }
    }
}

// ------- edge scores: pE[i][h] = exp(lrelu(aS+aD)-SHIFT), rinv[n][h] = 1/sum -------
__global__ __launch_bounds__(256) void k_score(
        const float* __restrict__ aS, const float* __restrict__ aD,
        const int* __restrict__ offs, const int* __restrict__ srcs,
        float* __restrict__ pE, float* __restrict__ rinv) {
    const int wid = threadIdx.x >> 6, lane = threadIdx.x & 63;
    const int node = blockIdx.x * 4 + wid;   // 2500*4 == NN
    const int h = lane & 31, el = lane >> 5;
    const int beg = offs[node], end = offs[node + 1];
    const float ad = aD[node * NH + h];
    float ssum = 0.f;
    for (int i = beg + el; i < end; i += 2) {
        int s = srcs[i];
        float sc = aS[s * NH + h] + ad;
        sc = (sc >= 0.f) ? sc : LRELU_SLOPE * sc;
        float p = __expf(sc - SM_SHIFT);
        pE[i * NH + h] = p;
        ssum += p;
    }
    ssum += __shfl_xor(ssum, 32);
    if (el == 0) rinv[node * NH + h] = 1.f / (ssum + SM_EPS);
}

// ------- XCD-sliced aggregation: pure gather+FMA (scores precomputed) -------
template<int C>
__global__ __launch_bounds__(256) void k_agg_slice(
        const bf16* __restrict__ XPB, const float* __restrict__ pE,
        const float* __restrict__ rinv, const int* __restrict__ offs,
        const int* __restrict__ srcs, float* __restrict__ P, int sg0) {
    constexpr int M = NH * C;       // xpb row length
    constexpr int HPS = 128 / C;    // heads per 128-col slice (2 or 4)
    constexpr int CGH = C / 8;      // col-groups per head (8 or 4)
    const int sg = sg0 + (blockIdx.x & 7);
    const int wid = threadIdx.x >> 6, lane = threadIdx.x & 63;
    const int node = (blockIdx.x >> 3) * 4 + wid;
    const int cg = lane & 15, el = lane >> 4;
    const int hl = cg / CGH;
    const int h = sg * HPS + hl;
    const int col = sg * 128 + cg * 8;
    const int beg = offs[node], end = offs[node + 1];
    float acc[8];
    #pragma unroll
    for (int j = 0; j < 8; j++) acc[j] = 0.f;
    int i = beg + el;
    int sN = 0; float pN = 0.f;
    if (i < end) { sN = srcs[i]; pN = pE[i * NH + h]; }
    while (i < end) {
        const int s = sN; const float p = pN;
        const int i2 = i + 4;
        if (i2 < end) { sN = srcs[i2]; pN = pE[i2 * NH + h]; }   // prefetch next
        uint4 v = *reinterpret_cast<const uint4*>(&XPB[s * M + col]);
        acc[0] = fmaf(p, asf(v.x << 16),          acc[0]);
        acc[1] = fmaf(p, asf(v.x & 0xffff0000u),  acc[1]);
        acc[2] = fmaf(p, asf(v.y << 16),          acc[2]);
        acc[3] = fmaf(p, asf(v.y & 0xffff0000u),  acc[3]);
        acc[4] = fmaf(p, asf(v.z << 16),          acc[4]);
        acc[5] = fmaf(p, asf(v.z & 0xffff0000u),  acc[5]);
        acc[6] = fmaf(p, asf(v.w << 16),          acc[6]);
        acc[7] = fmaf(p, asf(v.w & 0xffff0000u),  acc[7]);
        i = i2;
    }
    // reduce across the 4 edge-lanes (lane bits 4,5)
    #pragma unroll
    for (int j = 0; j < 8; j++) {
        acc[j] += __shfl_xor(acc[j], 16);
        acc[j] += __shfl_xor(acc[j], 32);
    }
    const float r = rinv[node * NH + h];
    #pragma unroll
    for (int j = 0; j < 8; j++) acc[j] *= r;     // per-head normalize BEFORE head-fold
    // fold the slice's heads onto shared output dims (cg bit 3 [, bit 2])
    #pragma unroll
    for (int j = 0; j < 8; j++) acc[j] += __shfl_xor(acc[j], 8);
    if constexpr (HPS == 4) {
        #pragma unroll
        for (int j = 0; j < 8; j++) acc[j] += __shfl_xor(acc[j], 4);
    }
    if (el == 0 && cg < CGH) {
        float* dst = &P[((size_t)sg * NN + node) * C + cg * 8];
        *reinterpret_cast<float4*>(dst)     = make_float4(acc[0], acc[1], acc[2], acc[3]);
        *reinterpret_cast<float4*>(dst + 4) = make_float4(acc[4], acc[5], acc[6], acc[7]);
    }
}

// ------- slice-sum + head-mean + bias + ELU (+ z1 bf16 copy), float4 -------
template<int C, int NS, bool WZ>
__global__ void k_reduce(const float* __restrict__ P, const float* __restrict__ bias,
                         float* __restrict__ out, int col0, bf16* __restrict__ z1b) {
    constexpr int TPN = C / 4;
    const int tid = threadIdx.x;
    const int node = blockIdx.x * (256 / TPN) + tid / TPN;
    const int c = (tid % TPN) * 4;
    if (node >= NN) return;
    float4 s = make_float4(0.f, 0.f, 0.f, 0.f);
    #pragma unroll
    for (int sg = 0; sg < NS; sg++) {
        float4 v = *reinterpret_cast<const float4*>(&P[((size_t)sg * NN + node) * C + c]);
        s.x += v.x; s.y += v.y; s.z += v.z; s.w += v.w;
    }
    float4 b = *reinterpret_cast<const float4*>(&bias[c]);
    s.x = s.x * (1.0f / NH) + b.x;
    s.y = s.y * (1.0f / NH) + b.y;
    s.z = s.z * (1.0f / NH) + b.z;
    s.w = s.w * (1.0f / NH) + b.w;
    s.x = (s.x > 0.f) ? s.x : expm1f(s.x);
    s.y = (s.y > 0.f) ? s.y : expm1f(s.y);
    s.z = (s.z > 0.f) ? s.z : expm1f(s.z);
    s.w = (s.w > 0.f) ? s.w : expm1f(s.w);
    *reinterpret_cast<float4*>(&out[(size_t)node * 96 + col0 + c]) = s;
    if constexpr (WZ) {
        bf16 hx[4] = {__float2bfloat16(s.x), __float2bfloat16(s.y),
                      __float2bfloat16(s.z), __float2bfloat16(s.w)};
        *reinterpret_cast<uint2*>(&z1b[(size_t)node * C + c]) =
            *reinterpret_cast<const uint2*>(hx);
    }
}

extern "C" void kernel_launch(void* const* d_in, const int* in_sizes, int n_in,
                              void* d_out, int out_size, void* d_ws, size_t ws_size,
                              hipStream_t stream) {
    const float* x   = (const float*)d_in[0];
    const int*   ei  = (const int*)d_in[1];
    const float* W1  = (const float*)d_in[2];
    const float* as1 = (const float*)d_in[3];
    const float* ad1 = (const float*)d_in[4];
    const float* b1  = (const float*)d_in[5];
    const float* W2  = (const float*)d_in[6];
    const float* as2 = (const float*)d_in[7];
    const float* ad2 = (const float*)d_in[8];
    const float* b2  = (const float*)d_in[9];
    float* out = (float*)d_out;

    char* w = (char*)d_ws;
    size_t off = 0;
    auto alloc = [&](size_t bytes) -> void* {
        void* p = w + off;
        off = (off + bytes + 255) & ~(size_t)255;
        return p;
    };
    bf16*  xpb    = (bf16*)alloc((size_t)NN * 2048 * 2);    // reused for layer2
    float* aS     = (float*)alloc((size_t)NN * NH * 4);
    float* aD     = (float*)alloc((size_t)NN * NH * 4);
    float* pE     = (float*)alloc((size_t)NE * NH * 4);     // reused for layer2
    float* rinv   = (float*)alloc((size_t)NN * NH * 4);
    float* P1     = (float*)alloc((size_t)16 * NN * 64 * 4);
    float* P2     = P1;                                      // alias: P1 dead after reduce1
    int*   deg    = (int*)alloc((size_t)NN * 4);
    int*   cursor = (int*)alloc((size_t)NN * 4);
    int*   offs   = (int*)alloc((size_t)(NN + 1) * 4);
    int*   srcs   = (int*)alloc((size_t)NE * 4);
    int*   srcv   = (int*)alloc((size_t)NE * 4);
    int*   dstv   = (int*)alloc((size_t)NE * 4);
    bf16*  Xb     = (bf16*)alloc((size_t)NN * 128 * 2);
    bf16*  Wt1    = (bf16*)alloc((size_t)2048 * 128 * 2);
    bf16*  Wt2    = (bf16*)alloc((size_t)1024 * 64 * 2);
    bf16*  z1b    = (bf16*)alloc((size_t)NN * 64 * 2);
    int*   eflag  = (int*)alloc(256);
    (void)ws_size; (void)in_sizes; (void)n_in; (void)out_size;

    // edges + CSR
    k_detect_zero<<<(NN + 255) / 256, 256, 0, stream>>>((const unsigned int*)ei, eflag, deg);
    k_norm_hist<<<NE / 256, 256, 0, stream>>>(ei, eflag, srcv, dstv, deg);
    k_scan<<<1, 1024, 0, stream>>>(deg, offs, cursor);
    k_scatter<<<NE / 256, 256, 0, stream>>>(srcv, dstv, cursor, srcs);

    // bf16 operand prep (one kernel)
    k_prep<<<(NN * 128 + 128 * 2048 + 64 * 1024 + 255) / 256, 256, 0, stream>>>(
        x, Xb, W1, Wt1, W2, Wt2);

    // ---- Layer 1: K=128, C=64, M=2048 ----
    k_gemm_mfma<128, 2048, 64><<<dim3((NN + 63) / 64, 2048 / 128), 256, 0, stream>>>(
        Xb, Wt1, as1, ad1, xpb, aS, aD);
    k_score<<<NN / 4, 256, 0, stream>>>(aS, aD, offs, srcs, pE, rinv);
    k_agg_slice<64><<<(NN / 4) * 8, 256, 0, stream>>>(xpb, pE, rinv, offs, srcs, P1, 0);
    k_agg_slice<64><<<(NN / 4) * 8, 256, 0, stream>>>(xpb, pE, rinv, offs, srcs, P1, 8);
    k_reduce<64, 16, true><<<NN / 16, 256, 0, stream>>>(P1, b1, out, 0, z1b);

    // ---- Layer 2: K=64, C=32, M=1024 ----
    k_gemm_mfma<64, 1024, 32><<<dim3((NN + 63) / 64, 1024 / 128), 256, 0, stream>>>(
        z1b, Wt2, as2, ad2, xpb, aS, aD);
    k_score<<<NN / 4, 256, 0, stream>>>(aS, aD, offs, srcs, pE, rinv);
    k_agg_slice<32><<<(NN / 4) * 8, 256, 0, stream>>>(xpb, pE, rinv, offs, srcs, P2, 0);
    k_reduce<32, 8, false><<<(NN * 8 + 255) / 256, 256, 0, stream>>>(P2, b2, out, 64, nullptr);
}

// Round 8
// 237.573 us; speedup vs baseline: 1.1619x; 1.1619x over previous
//
#include <hip/hip_runtime.h>
#include <hip/hip_bf16.h>

#define NN 10000
#define NE 160000
#define NH 32
#define LRELU_SLOPE 0.2f
#define SM_EPS 1e-16f
#define SM_SHIFT 16.0f

typedef __hip_bfloat16 bf16;
typedef __attribute__((ext_vector_type(8))) __bf16 bf16x8;
typedef __attribute__((ext_vector_type(4))) float f32x4;

__device__ __forceinline__ float asf(unsigned int u) {
    union { unsigned int u; float f; } v; v.u = u; return v.f;
}

// ---------------- detect edge dtype + zero deg ----------------
__global__ void k_detect_zero(const unsigned int* __restrict__ raw, int* __restrict__ flag,
                              int* __restrict__ deg) {
    int i = blockIdx.x * blockDim.x + threadIdx.x;
    if (i < NN) deg[i] = 0;
    if (i == 0) {
        int z = 1;
        for (int j = 1; j < 32; j += 2) z &= (raw[j] == 0u);
        *flag = z;   // 1 => int64
    }
}
// ---------------- normalize edges + histogram ----------------
__global__ void k_norm_hist(const int* __restrict__ raw, const int* __restrict__ flag,
                            int* __restrict__ srcv, int* __restrict__ dstv, int* __restrict__ deg) {
    int e = blockIdx.x * blockDim.x + threadIdx.x;
    if (e >= NE) return;
    int s, d;
    if (*flag) { s = raw[2 * e]; d = raw[2 * (NE + e)]; }
    else       { s = raw[e];     d = raw[NE + e]; }
    srcv[e] = s; dstv[e] = d;
    atomicAdd(&deg[d], 1);
}
// shfl-based scan, 1024 threads, 10 chunks
__global__ void k_scan(const int* __restrict__ deg, int* __restrict__ offs, int* __restrict__ cursor) {
    __shared__ int wsum[16], wpre[16];
    __shared__ int base;
    const int tid = threadIdx.x, lane = tid & 63, wid = tid >> 6;
    if (tid == 0) base = 0;
    __syncthreads();
    for (int chunk = 0; chunk < NN; chunk += 1024) {
        int idx = chunk + tid;
        int v = (idx < NN) ? deg[idx] : 0;
        int s = v;
        #pragma unroll
        for (int off = 1; off < 64; off <<= 1) {
            int t = __shfl_up(s, off);
            if (lane >= off) s += t;
        }
        if (lane == 63) wsum[wid] = s;
        __syncthreads();
        if (wid == 0) {
            int ws = (lane < 16) ? wsum[lane] : 0;
            #pragma unroll
            for (int off = 1; off < 16; off <<= 1) {
                int t = __shfl_up(ws, off);
                if (lane >= off) ws += t;
            }
            if (lane < 16) wpre[lane] = ws;
        }
        __syncthreads();
        int wbase = (wid == 0) ? 0 : wpre[wid - 1];
        int excl = base + wbase + s - v;
        if (idx < NN) { offs[idx] = excl; cursor[idx] = excl; }
        int total = wpre[15];
        __syncthreads();
        if (tid == 0) base += total;
        __syncthreads();
    }
    if (tid == 0) offs[NN] = base;
}
// scatter: CSR-ordered src list + CSR-position dst node
__global__ void k_scatter(const int* __restrict__ srcv, const int* __restrict__ dstv,
                          int* __restrict__ cursor, int* __restrict__ srcs,
                          int* __restrict__ dstp) {
    int e = blockIdx.x * blockDim.x + threadIdx.x;
    if (e < NE) {
        int d = dstv[e];
        int p = atomicAdd(&cursor[d], 1);
        srcs[p] = srcv[e];
        dstp[p] = d;
    }
}

// ---------------- fused prep: cast X, transpose W1, transpose W2 ----------------
__global__ void k_prep(const float* __restrict__ X, bf16* __restrict__ Xb,
                       const float* __restrict__ W1, bf16* __restrict__ Wt1,
                       const float* __restrict__ W2, bf16* __restrict__ Wt2) {
    int i = blockIdx.x * blockDim.x + threadIdx.x;
    if (i < NN * 128) { Xb[i] = __float2bfloat16(X[i]); return; }
    i -= NN * 128;
    if (i < 128 * 2048) {
        int k = i / 2048, m = i - k * 2048;
        Wt1[(size_t)m * 128 + k] = __float2bfloat16(W1[i]);
        return;
    }
    i -= 128 * 2048;
    if (i < 64 * 1024) {
        int k = i / 1024, m = i - k * 1024;
        Wt2[(size_t)m * 64 + k] = __float2bfloat16(W2[i]);
    }
}

// ------- MFMA GEMM: XPB[n, M](bf16) = Xb[n, :K] @ Wt^T; fused alpha dots -------
template<int K, int M, int C>
__global__ __launch_bounds__(256) void k_gemm_mfma(
        const bf16* __restrict__ Xb, const bf16* __restrict__ Wt,
        const float* __restrict__ Asrc, const float* __restrict__ Adst,
        bf16* __restrict__ XPB, float* __restrict__ aS, float* __restrict__ aD) {
    constexpr int BM = 64, BN = 128;
    constexpr int KB = K * 2;            // LDS row bytes
    constexpr int NHB = BN / C;          // heads per block (2 or 4)
    constexpr int WPH = C / 32;          // waves per head  (2 or 1)
    __shared__ char lds[(BM + BN) * KB];
    __shared__ float sredS[4][BM], sredD[4][BM];
    char* lA = lds;
    char* lB = lds + BM * KB;

    const int tid = threadIdx.x;
    const int wv = tid >> 6, ln = tid & 63;
    const int lrow = ln & 15, lkb = ln >> 4;
    const int brow = blockIdx.x * BM;
    const int bcol = blockIdx.y * BN;

    #pragma unroll
    for (int c = 0; c < BM * K / 8 / 256; c++) {
        int it = c * 256 + tid;
        int r = it / (K / 8), kc = (it % (K / 8)) * 8;
        int node = brow + r;
        uint4 v = make_uint4(0u, 0u, 0u, 0u);
        if (node < NN) v = *reinterpret_cast<const uint4*>(&Xb[(size_t)node * K + kc]);
        *reinterpret_cast<uint4*>(lA + ((r * KB + kc * 2) ^ ((r & 7) << 4))) = v;
    }
    #pragma unroll
    for (int c = 0; c < BN * K / 8 / 256; c++) {
        int it = c * 256 + tid;
        int r = it / (K / 8), kc = (it % (K / 8)) * 8;
        uint4 v = *reinterpret_cast<const uint4*>(&Wt[(size_t)(bcol + r) * K + kc]);
        *reinterpret_cast<uint4*>(lB + ((r * KB + kc * 2) ^ ((r & 7) << 4))) = v;
    }
    __syncthreads();

    f32x4 acc[4][2];
    #pragma unroll
    for (int mi = 0; mi < 4; mi++)
        #pragma unroll
        for (int nj = 0; nj < 2; nj++) acc[mi][nj] = (f32x4){0.f, 0.f, 0.f, 0.f};

    #pragma unroll
    for (int ks = 0; ks < K / 32; ks++) {
        const int k0 = ks * 32 + lkb * 8;
        bf16x8 af[4], bfr[2];
        #pragma unroll
        for (int mi = 0; mi < 4; mi++) {
            int r = mi * 16 + lrow;
            af[mi] = *reinterpret_cast<const bf16x8*>(lA + ((r * KB + k0 * 2) ^ ((r & 7) << 4)));
        }
        #pragma unroll
        for (int nj = 0; nj < 2; nj++) {
            int r = wv * 32 + nj * 16 + lrow;
            bfr[nj] = *reinterpret_cast<const bf16x8*>(lB + ((r * KB + k0 * 2) ^ ((r & 7) << 4)));
        }
        #pragma unroll
        for (int mi = 0; mi < 4; mi++)
            #pragma unroll
            for (int nj = 0; nj < 2; nj++)
                acc[mi][nj] = __builtin_amdgcn_mfma_f32_16x16x32_bf16(af[mi], bfr[nj], acc[mi][nj], 0, 0, 0);
    }

    // epilogue: D col = lane&15, row = (lane>>4)*4 + reg  [m89]
    float ar0 = Asrc[bcol + wv * 32 + lrow];
    float ar1 = Asrc[bcol + wv * 32 + 16 + lrow];
    float ad0 = Adst[bcol + wv * 32 + lrow];
    float ad1 = Adst[bcol + wv * 32 + 16 + lrow];

    #pragma unroll
    for (int mi = 0; mi < 4; mi++) {
        #pragma unroll
        for (int r = 0; r < 4; r++) {
            int rowl = mi * 16 + lkb * 4 + r;
            int row = brow + rowl;
            if (row < NN) {
                XPB[(size_t)row * M + bcol + wv * 32 + lrow]      = __float2bfloat16(acc[mi][0][r]);
                XPB[(size_t)row * M + bcol + wv * 32 + 16 + lrow] = __float2bfloat16(acc[mi][1][r]);
            }
            float vs = acc[mi][0][r] * ar0 + acc[mi][1][r] * ar1;
            float vd = acc[mi][0][r] * ad0 + acc[mi][1][r] * ad1;
            vs += __shfl_xor(vs, 1); vd += __shfl_xor(vd, 1);
            vs += __shfl_xor(vs, 2); vd += __shfl_xor(vd, 2);
            vs += __shfl_xor(vs, 4); vd += __shfl_xor(vd, 4);
            vs += __shfl_xor(vs, 8); vd += __shfl_xor(vd, 8);
            if (lrow == 0) {
                sredS[wv][rowl] = vs;
                sredD[wv][rowl] = vd;
            }
        }
    }
    __syncthreads();
    if (tid < BM) {
        int node = brow + tid;
        if (node < NN) {
            #pragma unroll
            for (int hb = 0; hb < NHB; hb++) {
                float ss = 0.f, dd = 0.f;
                #pragma unroll
                for (int w = 0; w < WPH; w++) {
                    ss += sredS[hb * WPH + w][tid];
                    dd += sredD[hb * WPH + w][tid];
                }
                int h = bcol / C + hb;
                aS[node * NH + h] = ss;
                aD[node * NH + h] = dd;
            }
        }
    }
}

// ------- edge-parallel scores, transposed output pEh[h][i] -------
// thread = CSR position; 160K independent threads (full MLP, no serial chains).
__global__ __launch_bounds__(256) void k_score_edge(
        const float* __restrict__ aS, const float* __restrict__ aD,
        const int* __restrict__ srcs, const int* __restrict__ dstp,
        float* __restrict__ pEh) {
    const int i = blockIdx.x * 256 + threadIdx.x;   // NE = 625*256 exact
    const int s = srcs[i];
    const int d = dstp[i];
    const float4* prs = reinterpret_cast<const float4*>(&aS[s * NH]);
    const float4* prd = reinterpret_cast<const float4*>(&aD[d * NH]);
    float4 vs[8], vd[8];
    #pragma unroll
    for (int j = 0; j < 8; j++) { vs[j] = prs[j]; vd[j] = prd[j]; }
    #pragma unroll
    for (int j = 0; j < 8; j++) {
        float sc, p;
        sc = vs[j].x + vd[j].x; sc = (sc >= 0.f) ? sc : LRELU_SLOPE * sc;
        p = __expf(sc - SM_SHIFT); pEh[(size_t)(4 * j + 0) * NE + i] = p;
        sc = vs[j].y + vd[j].y; sc = (sc >= 0.f) ? sc : LRELU_SLOPE * sc;
        p = __expf(sc - SM_SHIFT); pEh[(size_t)(4 * j + 1) * NE + i] = p;
        sc = vs[j].z + vd[j].z; sc = (sc >= 0.f) ? sc : LRELU_SLOPE * sc;
        p = __expf(sc - SM_SHIFT); pEh[(size_t)(4 * j + 2) * NE + i] = p;
        sc = vs[j].w + vd[j].w; sc = (sc >= 0.f) ? sc : LRELU_SLOPE * sc;
        p = __expf(sc - SM_SHIFT); pEh[(size_t)(4 * j + 3) * NE + i] = p;
    }
}

// ------- XCD-sliced aggregation: gather+FMA, ssum folded in -------
template<int C>
__global__ __launch_bounds__(256) void k_agg_slice(
        const bf16* __restrict__ XPB, const float* __restrict__ pEh,
        const int* __restrict__ offs, const int* __restrict__ srcs,
        float* __restrict__ P, int sg0) {
    constexpr int M = NH * C;       // xpb row length
    constexpr int HPS = 128 / C;    // heads per 128-col slice (2 or 4)
    constexpr int CGH = C / 8;      // col-groups per head (8 or 4)
    const int sg = sg0 + (blockIdx.x & 7);
    const int wid = threadIdx.x >> 6, lane = threadIdx.x & 63;
    const int node = (blockIdx.x >> 3) * 4 + wid;
    const int cg = lane & 15, el = lane >> 4;
    const int hl = cg / CGH;
    const int h = sg * HPS + hl;
    const int col = sg * 128 + cg * 8;
    const int beg = offs[node], end = offs[node + 1];
    const float* __restrict__ pErow = pEh + (size_t)h * NE;
    float acc[8];
    #pragma unroll
    for (int j = 0; j < 8; j++) acc[j] = 0.f;
    float ssum = 0.f;
    int i = beg + el;
    int sN = 0; float pN = 0.f;
    if (i < end) { sN = srcs[i]; pN = pErow[i]; }
    while (i < end) {
        const int s = sN; const float p = pN;
        const int i2 = i + 4;
        if (i2 < end) { sN = srcs[i2]; pN = pErow[i2]; }   // prefetch next
        uint4 v = *reinterpret_cast<const uint4*>(&XPB[(size_t)s * M + col]);
        ssum += p;
        acc[0] = fmaf(p, asf(v.x << 16),          acc[0]);
        acc[1] = fmaf(p, asf(v.x & 0xffff0000u),  acc[1]);
        acc[2] = fmaf(p, asf(v.y << 16),          acc[2]);
        acc[3] = fmaf(p, asf(v.y & 0xffff0000u),  acc[3]);
        acc[4] = fmaf(p, asf(v.z << 16),          acc[4]);
        acc[5] = fmaf(p, asf(v.z & 0xffff0000u),  acc[5]);
        acc[6] = fmaf(p, asf(v.w << 16),          acc[6]);
        acc[7] = fmaf(p, asf(v.w & 0xffff0000u),  acc[7]);
        i = i2;
    }
    // reduce across the 4 edge-lanes (lane bits 4,5)
    #pragma unroll
    for (int j = 0; j < 8; j++) {
        acc[j] += __shfl_xor(acc[j], 16);
        acc[j] += __shfl_xor(acc[j], 32);
    }
    ssum += __shfl_xor(ssum, 16);
    ssum += __shfl_xor(ssum, 32);
    const float r = 1.f / (ssum + SM_EPS);
    #pragma unroll
    for (int j = 0; j < 8; j++) acc[j] *= r;     // per-head normalize BEFORE head-fold
    // fold the slice's heads onto shared output dims (cg bit 3 [, bit 2])
    #pragma unroll
    for (int j = 0; j < 8; j++) acc[j] += __shfl_xor(acc[j], 8);
    if constexpr (HPS == 4) {
        #pragma unroll
        for (int j = 0; j < 8; j++) acc[j] += __shfl_xor(acc[j], 4);
    }
    if (el == 0 && cg < CGH) {
        float* dst = &P[((size_t)sg * NN + node) * C + cg * 8];
        *reinterpret_cast<float4*>(dst)     = make_float4(acc[0], acc[1], acc[2], acc[3]);
        *reinterpret_cast<float4*>(dst + 4) = make_float4(acc[4], acc[5], acc[6], acc[7]);
    }
}

// ------- slice-sum + head-mean + bias + ELU (+ z1 bf16 copy), float4 -------
template<int C, int NS, bool WZ>
__global__ void k_reduce(const float* __restrict__ P, const float* __restrict__ bias,
                         float* __restrict__ out, int col0, bf16* __restrict__ z1b) {
    constexpr int TPN = C / 4;
    const int tid = threadIdx.x;
    const int node = blockIdx.x * (256 / TPN) + tid / TPN;
    const int c = (tid % TPN) * 4;
    if (node >= NN) return;
    float4 s = make_float4(0.f, 0.f, 0.f, 0.f);
    #pragma unroll
    for (int sg = 0; sg < NS; sg++) {
        float4 v = *reinterpret_cast<const float4*>(&P[((size_t)sg * NN + node) * C + c]);
        s.x += v.x; s.y += v.y; s.z += v.z; s.w += v.w;
    }
    float4 b = *reinterpret_cast<const float4*>(&bias[c]);
    s.x = s.x * (1.0f / NH) + b.x;
    s.y = s.y * (1.0f / NH) + b.y;
    s.z = s.z * (1.0f / NH) + b.z;
    s.w = s.w * (1.0f / NH) + b.w;
    s.x = (s.x > 0.f) ? s.x : expm1f(s.x);
    s.y = (s.y > 0.f) ? s.y : expm1f(s.y);
    s.z = (s.z > 0.f) ? s.z : expm1f(s.z);
    s.w = (s.w > 0.f) ? s.w : expm1f(s.w);
    *reinterpret_cast<float4*>(&out[(size_t)node * 96 + col0 + c]) = s;
    if constexpr (WZ) {
        bf16 hx[4] = {__float2bfloat16(s.x), __float2bfloat16(s.y),
                      __float2bfloat16(s.z), __float2bfloat16(s.w)};
        *reinterpret_cast<uint2*>(&z1b[(size_t)node * C + c]) =
            *reinterpret_cast<const uint2*>(hx);
    }
}

extern "C" void kernel_launch(void* const* d_in, const int* in_sizes, int n_in,
                              void* d_out, int out_size, void* d_ws, size_t ws_size,
                              hipStream_t stream) {
    const float* x   = (const float*)d_in[0];
    const int*   ei  = (const int*)d_in[1];
    const float* W1  = (const float*)d_in[2];
    const float* as1 = (const float*)d_in[3];
    const float* ad1 = (const float*)d_in[4];
    const float* b1  = (const float*)d_in[5];
    const float* W2  = (const float*)d_in[6];
    const float* as2 = (const float*)d_in[7];
    const float* ad2 = (const float*)d_in[8];
    const float* b2  = (const float*)d_in[9];
    float* out = (float*)d_out;

    char* w = (char*)d_ws;
    size_t off = 0;
    auto alloc = [&](size_t bytes) -> void* {
        void* p = w + off;
        off = (off + bytes + 255) & ~(size_t)255;
        return p;
    };
    bf16*  xpb    = (bf16*)alloc((size_t)NN * 2048 * 2);    // reused for layer2
    float* aS     = (float*)alloc((size_t)NN * NH * 4);
    float* aD     = (float*)alloc((size_t)NN * NH * 4);
    float* pEh    = (float*)alloc((size_t)NH * NE * 4);     // transposed scores, reused L2
    float* P1     = (float*)alloc((size_t)16 * NN * 64 * 4);
    float* P2     = P1;                                      // alias: P1 dead after reduce1
    int*   deg    = (int*)alloc((size_t)NN * 4);
    int*   cursor = (int*)alloc((size_t)NN * 4);
    int*   offs   = (int*)alloc((size_t)(NN + 1) * 4);
    int*   srcs   = (int*)alloc((size_t)NE * 4);
    int*   dstp   = (int*)alloc((size_t)NE * 4);
    int*   srcv   = (int*)alloc((size_t)NE * 4);
    int*   dstv   = (int*)alloc((size_t)NE * 4);
    bf16*  Xb     = (bf16*)alloc((size_t)NN * 128 * 2);
    bf16*  Wt1    = (bf16*)alloc((size_t)2048 * 128 * 2);
    bf16*  Wt2    = (bf16*)alloc((size_t)1024 * 64 * 2);
    bf16*  z1b    = (bf16*)alloc((size_t)NN * 64 * 2);
    int*   eflag  = (int*)alloc(256);
    (void)ws_size; (void)in_sizes; (void)n_in; (void)out_size;

    // edges + CSR
    k_detect_zero<<<(NN + 255) / 256, 256, 0, stream>>>((const unsigned int*)ei, eflag, deg);
    k_norm_hist<<<NE / 256, 256, 0, stream>>>(ei, eflag, srcv, dstv, deg);
    k_scan<<<1, 1024, 0, stream>>>(deg, offs, cursor);
    k_scatter<<<NE / 256, 256, 0, stream>>>(srcv, dstv, cursor, srcs, dstp);

    // bf16 operand prep (one kernel)
    k_prep<<<(NN * 128 + 128 * 2048 + 64 * 1024 + 255) / 256, 256, 0, stream>>>(
        x, Xb, W1, Wt1, W2, Wt2);

    // ---- Layer 1: K=128, C=64, M=2048 ----
    k_gemm_mfma<128, 2048, 64><<<dim3((NN + 63) / 64, 2048 / 128), 256, 0, stream>>>(
        Xb, Wt1, as1, ad1, xpb, aS, aD);
    k_score_edge<<<NE / 256, 256, 0, stream>>>(aS, aD, srcs, dstp, pEh);
    k_agg_slice<64><<<(NN / 4) * 8, 256, 0, stream>>>(xpb, pEh, offs, srcs, P1, 0);
    k_agg_slice<64><<<(NN / 4) * 8, 256, 0, stream>>>(xpb, pEh, offs, srcs, P1, 8);
    k_reduce<64, 16, true><<<NN / 16, 256, 0, stream>>>(P1, b1, out, 0, z1b);

    // ---- Layer 2: K=64, C=32, M=1024 ----
    k_gemm_mfma<64, 1024, 32><<<dim3((NN + 63) / 64, 1024 / 128), 256, 0, stream>>>(
        z1b, Wt2, as2, ad2, xpb, aS, aD);
    k_score_edge<<<NE / 256, 256, 0, stream>>>(aS, aD, srcs, dstp, pEh);
    k_agg_slice<32><<<(NN / 4) * 8, 256, 0, stream>>>(xpb, pEh, offs, srcs, P2, 0);
    k_reduce<32, 8, false><<<(NN * 8 + 255) / 256, 256, 0, stream>>>(P2, b2, out, 64, nullptr);
}

// Round 9
// 233.240 us; speedup vs baseline: 1.1834x; 1.0186x over previous
//
#include <hip/hip_runtime.h>
#include <hip/hip_bf16.h>

#define NN 10000
#define NE 160000
#define NE_PAD 190464   // >= NE + 3*NN, multiple of 256
#define NH 32
#define LRELU_SLOPE 0.2f
#define SM_EPS 1e-16f
#define SM_SHIFT 16.0f

typedef __hip_bfloat16 bf16;
typedef __attribute__((ext_vector_type(8))) __bf16 bf16x8;
typedef __attribute__((ext_vector_type(4))) float f32x4;

__device__ __forceinline__ float asf(unsigned int u) {
    union { unsigned int u; float f; } v; v.u = u; return v.f;
}

// ---------------- detect edge dtype + zero deg ----------------
__global__ void k_detect_zero(const unsigned int* __restrict__ raw, int* __restrict__ flag,
                              int* __restrict__ deg) {
    int i = blockIdx.x * blockDim.x + threadIdx.x;
    if (i < NN) deg[i] = 0;
    if (i == 0) {
        int z = 1;
        for (int j = 1; j < 32; j += 2) z &= (raw[j] == 0u);
        *flag = z;   // 1 => int64
    }
}
// ---------------- normalize edges + histogram ----------------
__global__ void k_norm_hist(const int* __restrict__ raw, const int* __restrict__ flag,
                            int* __restrict__ srcv, int* __restrict__ dstv, int* __restrict__ deg) {
    int e = blockIdx.x * blockDim.x + threadIdx.x;
    if (e >= NE) return;
    int s, d;
    if (*flag) { s = raw[2 * e]; d = raw[2 * (NE + e)]; }
    else       { s = raw[e];     d = raw[NE + e]; }
    srcv[e] = s; dstv[e] = d;
    atomicAdd(&deg[d], 1);
}
// shfl-based scan over PADDED degree (roundup4), 1024 threads, 10 chunks
__global__ void k_scan(const int* __restrict__ deg, int* __restrict__ offs, int* __restrict__ cursor) {
    __shared__ int wsum[16], wpre[16];
    __shared__ int base;
    const int tid = threadIdx.x, lane = tid & 63, wid = tid >> 6;
    if (tid == 0) base = 0;
    __syncthreads();
    for (int chunk = 0; chunk < NN; chunk += 1024) {
        int idx = chunk + tid;
        int v = (idx < NN) ? ((deg[idx] + 3) & ~3) : 0;
        int s = v;
        #pragma unroll
        for (int off = 1; off < 64; off <<= 1) {
            int t = __shfl_up(s, off);
            if (lane >= off) s += t;
        }
        if (lane == 63) wsum[wid] = s;
        __syncthreads();
        if (wid == 0) {
            int ws = (lane < 16) ? wsum[lane] : 0;
            #pragma unroll
            for (int off = 1; off < 16; off <<= 1) {
                int t = __shfl_up(ws, off);
                if (lane >= off) ws += t;
            }
            if (lane < 16) wpre[lane] = ws;
        }
        __syncthreads();
        int wbase = (wid == 0) ? 0 : wpre[wid - 1];
        int excl = base + wbase + s - v;
        if (idx < NN) { offs[idx] = excl; cursor[idx] = excl; }
        int total = wpre[15];
        __syncthreads();
        if (tid == 0) base += total;
        __syncthreads();
    }
    if (tid == 0) offs[NN] = base;
}
// scatter: CSR-ordered src list + CSR-position dst node (into padded layout)
__global__ void k_scatter(const int* __restrict__ srcv, const int* __restrict__ dstv,
                          int* __restrict__ cursor, int* __restrict__ srcs,
                          int* __restrict__ dstp) {
    int e = blockIdx.x * blockDim.x + threadIdx.x;
    if (e < NE) {
        int d = dstv[e];
        int p = atomicAdd(&cursor[d], 1);
        srcs[p] = srcv[e];
        dstp[p] = d;
    }
}

// ---------------- fused prep: pad-fill srcs/dstp, cast X, transpose W1/W2 ----------------
__global__ void k_prep(const float* __restrict__ X, bf16* __restrict__ Xb,
                       const float* __restrict__ W1, bf16* __restrict__ Wt1,
                       const float* __restrict__ W2, bf16* __restrict__ Wt2,
                       int* __restrict__ srcs, int* __restrict__ dstp) {
    int i = blockIdx.x * blockDim.x + threadIdx.x;
    if (i < NE_PAD) { srcs[i] = 0; dstp[i] = -1; }   // scatter overwrites real slots
    if (i < NN * 128) { Xb[i] = __float2bfloat16(X[i]); return; }
    i -= NN * 128;
    if (i < 128 * 2048) {
        int k = i / 2048, m = i - k * 2048;
        Wt1[(size_t)m * 128 + k] = __float2bfloat16(W1[i]);
        return;
    }
    i -= 128 * 2048;
    if (i < 64 * 1024) {
        int k = i / 1024, m = i - k * 1024;
        Wt2[(size_t)m * 64 + k] = __float2bfloat16(W2[i]);
    }
}

// ------- MFMA GEMM: XPB[n, M](bf16) = Xb[n, :K] @ Wt^T; fused alpha dots -------
template<int K, int M, int C>
__global__ __launch_bounds__(256) void k_gemm_mfma(
        const bf16* __restrict__ Xb, const bf16* __restrict__ Wt,
        const float* __restrict__ Asrc, const float* __restrict__ Adst,
        bf16* __restrict__ XPB, float* __restrict__ aS, float* __restrict__ aD) {
    constexpr int BM = 64, BN = 128;
    constexpr int KB = K * 2;            // LDS row bytes
    constexpr int NHB = BN / C;          // heads per block (2 or 4)
    constexpr int WPH = C / 32;          // waves per head  (2 or 1)
    __shared__ char lds[(BM + BN) * KB];
    __shared__ float sredS[4][BM], sredD[4][BM];
    char* lA = lds;
    char* lB = lds + BM * KB;

    const int tid = threadIdx.x;
    const int wv = tid >> 6, ln = tid & 63;
    const int lrow = ln & 15, lkb = ln >> 4;
    const int brow = blockIdx.x * BM;
    const int bcol = blockIdx.y * BN;

    #pragma unroll
    for (int c = 0; c < BM * K / 8 / 256; c++) {
        int it = c * 256 + tid;
        int r = it / (K / 8), kc = (it % (K / 8)) * 8;
        int node = brow + r;
        uint4 v = make_uint4(0u, 0u, 0u, 0u);
        if (node < NN) v = *reinterpret_cast<const uint4*>(&Xb[(size_t)node * K + kc]);
        *reinterpret_cast<uint4*>(lA + ((r * KB + kc * 2) ^ ((r & 7) << 4))) = v;
    }
    #pragma unroll
    for (int c = 0; c < BN * K / 8 / 256; c++) {
        int it = c * 256 + tid;
        int r = it / (K / 8), kc = (it % (K / 8)) * 8;
        uint4 v = *reinterpret_cast<const uint4*>(&Wt[(size_t)(bcol + r) * K + kc]);
        *reinterpret_cast<uint4*>(lB + ((r * KB + kc * 2) ^ ((r & 7) << 4))) = v;
    }
    __syncthreads();

    f32x4 acc[4][2];
    #pragma unroll
    for (int mi = 0; mi < 4; mi++)
        #pragma unroll
        for (int nj = 0; nj < 2; nj++) acc[mi][nj] = (f32x4){0.f, 0.f, 0.f, 0.f};

    #pragma unroll
    for (int ks = 0; ks < K / 32; ks++) {
        const int k0 = ks * 32 + lkb * 8;
        bf16x8 af[4], bfr[2];
        #pragma unroll
        for (int mi = 0; mi < 4; mi++) {
            int r = mi * 16 + lrow;
            af[mi] = *reinterpret_cast<const bf16x8*>(lA + ((r * KB + k0 * 2) ^ ((r & 7) << 4)));
        }
        #pragma unroll
        for (int nj = 0; nj < 2; nj++) {
            int r = wv * 32 + nj * 16 + lrow;
            bfr[nj] = *reinterpret_cast<const bf16x8*>(lB + ((r * KB + k0 * 2) ^ ((r & 7) << 4)));
        }
        #pragma unroll
        for (int mi = 0; mi < 4; mi++)
            #pragma unroll
            for (int nj = 0; nj < 2; nj++)
                acc[mi][nj] = __builtin_amdgcn_mfma_f32_16x16x32_bf16(af[mi], bfr[nj], acc[mi][nj], 0, 0, 0);
    }

    // epilogue: D col = lane&15, row = (lane>>4)*4 + reg  [m89]
    float ar0 = Asrc[bcol + wv * 32 + lrow];
    float ar1 = Asrc[bcol + wv * 32 + 16 + lrow];
    float ad0 = Adst[bcol + wv * 32 + lrow];
    float ad1 = Adst[bcol + wv * 32 + 16 + lrow];

    #pragma unroll
    for (int mi = 0; mi < 4; mi++) {
        #pragma unroll
        for (int r = 0; r < 4; r++) {
            int rowl = mi * 16 + lkb * 4 + r;
            int row = brow + rowl;
            if (row < NN) {
                XPB[(size_t)row * M + bcol + wv * 32 + lrow]      = __float2bfloat16(acc[mi][0][r]);
                XPB[(size_t)row * M + bcol + wv * 32 + 16 + lrow] = __float2bfloat16(acc[mi][1][r]);
            }
            float vs = acc[mi][0][r] * ar0 + acc[mi][1][r] * ar1;
            float vd = acc[mi][0][r] * ad0 + acc[mi][1][r] * ad1;
            vs += __shfl_xor(vs, 1); vd += __shfl_xor(vd, 1);
            vs += __shfl_xor(vs, 2); vd += __shfl_xor(vd, 2);
            vs += __shfl_xor(vs, 4); vd += __shfl_xor(vd, 4);
            vs += __shfl_xor(vs, 8); vd += __shfl_xor(vd, 8);
            if (lrow == 0) {
                sredS[wv][rowl] = vs;
                sredD[wv][rowl] = vd;
            }
        }
    }
    __syncthreads();
    if (tid < BM) {
        int node = brow + tid;
        if (node < NN) {
            #pragma unroll
            for (int hb = 0; hb < NHB; hb++) {
                float ss = 0.f, dd = 0.f;
                #pragma unroll
                for (int w = 0; w < WPH; w++) {
                    ss += sredS[hb * WPH + w][tid];
                    dd += sredD[hb * WPH + w][tid];
                }
                int h = bcol / C + hb;
                aS[node * NH + h] = ss;
                aD[node * NH + h] = dd;
            }
        }
    }
}

// ------- edge-parallel scores, transposed output pEh[h][i] (padded) -------
__global__ __launch_bounds__(256) void k_score_edge(
        const float* __restrict__ aS, const float* __restrict__ aD,
        const int* __restrict__ srcs, const int* __restrict__ dstp,
        float* __restrict__ pEh) {
    const int i = blockIdx.x * 256 + threadIdx.x;   // NE_PAD = 744*256 exact
    const int d = dstp[i];
    if (d < 0) {                                    // pad slot -> p = 0
        #pragma unroll
        for (int h = 0; h < NH; h++) pEh[(size_t)h * NE_PAD + i] = 0.f;
        return;
    }
    const int s = srcs[i];
    const float4* prs = reinterpret_cast<const float4*>(&aS[s * NH]);
    const float4* prd = reinterpret_cast<const float4*>(&aD[d * NH]);
    float4 vs[8], vd[8];
    #pragma unroll
    for (int j = 0; j < 8; j++) { vs[j] = prs[j]; vd[j] = prd[j]; }
    #pragma unroll
    for (int j = 0; j < 8; j++) {
        float sc, p;
        sc = vs[j].x + vd[j].x; sc = (sc >= 0.f) ? sc : LRELU_SLOPE * sc;
        p = __expf(sc - SM_SHIFT); pEh[(size_t)(4 * j + 0) * NE_PAD + i] = p;
        sc = vs[j].y + vd[j].y; sc = (sc >= 0.f) ? sc : LRELU_SLOPE * sc;
        p = __expf(sc - SM_SHIFT); pEh[(size_t)(4 * j + 1) * NE_PAD + i] = p;
        sc = vs[j].z + vd[j].z; sc = (sc >= 0.f) ? sc : LRELU_SLOPE * sc;
        p = __expf(sc - SM_SHIFT); pEh[(size_t)(4 * j + 2) * NE_PAD + i] = p;
        sc = vs[j].w + vd[j].w; sc = (sc >= 0.f) ? sc : LRELU_SLOPE * sc;
        p = __expf(sc - SM_SHIFT); pEh[(size_t)(4 * j + 3) * NE_PAD + i] = p;
    }
}

// ------- XCD-sliced aggregation: branchless uniform-trip gather+FMA -------
// Pad slots contribute p=0 (score kernel) and gather row 0 (cache-hot).
template<int C>
__global__ __launch_bounds__(256) void k_agg_slice(
        const bf16* __restrict__ XPB, const float* __restrict__ pEh,
        const int* __restrict__ offs, const int* __restrict__ srcs,
        float* __restrict__ P) {
    constexpr int M = NH * C;       // xpb row length
    constexpr int HPS = 128 / C;    // heads per 128-col slice (2 or 4)
    constexpr int CGH = C / 8;      // col-groups per head (8 or 4)
    constexpr int HGRID = (NN / 4) * 8;
    int b = blockIdx.x;
    const int hp = (b >= HGRID) ? 1 : 0;   // second half of merged launch -> sg 8..15
    b -= hp * HGRID;
    const int sg = (b & 7) + hp * 8;
    const int wid = threadIdx.x >> 6, lane = threadIdx.x & 63;
    const int node = (b >> 3) * 4 + wid;
    const int cg = lane & 15, el = lane >> 4;
    const int hl = cg / CGH;
    const int h = sg * HPS + hl;
    const int col = sg * 128 + cg * 8;
    const int beg = offs[node], end = offs[node + 1];   // padded: (end-beg)%4 == 0
    const float* __restrict__ pErow = pEh + (size_t)h * NE_PAD;
    float acc[8];
    #pragma unroll
    for (int j = 0; j < 8; j++) acc[j] = 0.f;
    float ssum = 0.f;
    int i = beg + el;
    const int trip = (end - beg) >> 2;      // uniform across wave
    #define AGG_STEP(ii) { \
        const int s_ = srcs[ii]; const float p_ = pErow[ii]; \
        uint4 v_ = *reinterpret_cast<const uint4*>(&XPB[(size_t)s_ * M + col]); \
        ssum += p_; \
        acc[0] = fmaf(p_, asf(v_.x << 16),         acc[0]); \
        acc[1] = fmaf(p_, asf(v_.x & 0xffff0000u), acc[1]); \
        acc[2] = fmaf(p_, asf(v_.y << 16),         acc[2]); \
        acc[3] = fmaf(p_, asf(v_.y & 0xffff0000u), acc[3]); \
        acc[4] = fmaf(p_, asf(v_.z << 16),         acc[4]); \
        acc[5] = fmaf(p_, asf(v_.z & 0xffff0000u), acc[5]); \
        acc[6] = fmaf(p_, asf(v_.w << 16),         acc[6]); \
        acc[7] = fmaf(p_, asf(v_.w & 0xffff0000u), acc[7]); }
    if (trip & 1) { AGG_STEP(i); i += 4; }
    for (int t = trip >> 1; t > 0; t--) {   // 2-wide: two independent gathers in flight
        AGG_STEP(i);
        AGG_STEP(i + 4);
        i += 8;
    }
    #undef AGG_STEP
    // reduce across the 4 edge-lanes (lane bits 4,5)
    #pragma unroll
    for (int j = 0; j < 8; j++) {
        acc[j] += __shfl_xor(acc[j], 16);
        acc[j] += __shfl_xor(acc[j], 32);
    }
    ssum += __shfl_xor(ssum, 16);
    ssum += __shfl_xor(ssum, 32);
    const float r = 1.f / (ssum + SM_EPS);
    #pragma unroll
    for (int j = 0; j < 8; j++) acc[j] *= r;     // per-head normalize BEFORE head-fold
    // fold the slice's heads onto shared output dims (cg bit 3 [, bit 2])
    #pragma unroll
    for (int j = 0; j < 8; j++) acc[j] += __shfl_xor(acc[j], 8);
    if constexpr (HPS == 4) {
        #pragma unroll
        for (int j = 0; j < 8; j++) acc[j] += __shfl_xor(acc[j], 4);
    }
    if (el == 0 && cg < CGH) {
        float* dst = &P[((size_t)sg * NN + node) * C + cg * 8];
        *reinterpret_cast<float4*>(dst)     = make_float4(acc[0], acc[1], acc[2], acc[3]);
        *reinterpret_cast<float4*>(dst + 4) = make_float4(acc[4], acc[5], acc[6], acc[7]);
    }
}

// ------- slice-sum + head-mean + bias + ELU (+ z1 bf16 copy), float4 -------
template<int C, int NS, bool WZ>
__global__ void k_reduce(const float* __restrict__ P, const float* __restrict__ bias,
                         float* __restrict__ out, int col0, bf16* __restrict__ z1b) {
    constexpr int TPN = C / 4;
    const int tid = threadIdx.x;
    const int node = blockIdx.x * (256 / TPN) + tid / TPN;
    const int c = (tid % TPN) * 4;
    if (node >= NN) return;
    float4 s = make_float4(0.f, 0.f, 0.f, 0.f);
    #pragma unroll
    for (int sg = 0; sg < NS; sg++) {
        float4 v = *reinterpret_cast<const float4*>(&P[((size_t)sg * NN + node) * C + c]);
        s.x += v.x; s.y += v.y; s.z += v.z; s.w += v.w;
    }
    float4 b = *reinterpret_cast<const float4*>(&bias[c]);
    s.x = s.x * (1.0f / NH) + b.x;
    s.y = s.y * (1.0f / NH) + b.y;
    s.z = s.z * (1.0f / NH) + b.z;
    s.w = s.w * (1.0f / NH) + b.w;
    s.x = (s.x > 0.f) ? s.x : expm1f(s.x);
    s.y = (s.y > 0.f) ? s.y : expm1f(s.y);
    s.z = (s.z > 0.f) ? s.z : expm1f(s.z);
    s.w = (s.w > 0.f) ? s.w : expm1f(s.w);
    *reinterpret_cast<float4*>(&out[(size_t)node * 96 + col0 + c]) = s;
    if constexpr (WZ) {
        bf16 hx[4] = {__float2bfloat16(s.x), __float2bfloat16(s.y),
                      __float2bfloat16(s.z), __float2bfloat16(s.w)};
        *reinterpret_cast<uint2*>(&z1b[(size_t)node * C + c]) =
            *reinterpret_cast<const uint2*>(hx);
    }
}

extern "C" void kernel_launch(void* const* d_in, const int* in_sizes, int n_in,
                              void* d_out, int out_size, void* d_ws, size_t ws_size,
                              hipStream_t stream) {
    const float* x   = (const float*)d_in[0];
    const int*   ei  = (const int*)d_in[1];
    const float* W1  = (const float*)d_in[2];
    const float* as1 = (const float*)d_in[3];
    const float* ad1 = (const float*)d_in[4];
    const float* b1  = (const float*)d_in[5];
    const float* W2  = (const float*)d_in[6];
    const float* as2 = (const float*)d_in[7];
    const float* ad2 = (const float*)d_in[8];
    const float* b2  = (const float*)d_in[9];
    float* out = (float*)d_out;

    char* w = (char*)d_ws;
    size_t off = 0;
    auto alloc = [&](size_t bytes) -> void* {
        void* p = w + off;
        off = (off + bytes + 255) & ~(size_t)255;
        return p;
    };
    bf16*  xpb    = (bf16*)alloc((size_t)NN * 2048 * 2);    // reused for layer2
    float* aS     = (float*)alloc((size_t)NN * NH * 4);
    float* aD     = (float*)alloc((size_t)NN * NH * 4);
    float* pEh    = (float*)alloc((size_t)NH * NE_PAD * 4); // transposed scores (padded)
    float* P1     = (float*)alloc((size_t)16 * NN * 64 * 4);
    float* P2     = P1;                                      // alias: P1 dead after reduce1
    int*   deg    = (int*)alloc((size_t)NN * 4);
    int*   cursor = (int*)alloc((size_t)NN * 4);
    int*   offs   = (int*)alloc((size_t)(NN + 1) * 4);
    int*   srcs   = (int*)alloc((size_t)NE_PAD * 4);
    int*   dstp   = (int*)alloc((size_t)NE_PAD * 4);
    int*   srcv   = (int*)alloc((size_t)NE * 4);
    int*   dstv   = (int*)alloc((size_t)NE * 4);
    bf16*  Xb     = (bf16*)alloc((size_t)NN * 128 * 2);
    bf16*  Wt1    = (bf16*)alloc((size_t)2048 * 128 * 2);
    bf16*  Wt2    = (bf16*)alloc((size_t)1024 * 64 * 2);
    bf16*  z1b    = (bf16*)alloc((size_t)NN * 64 * 2);
    int*   eflag  = (int*)alloc(256);
    (void)ws_size; (void)in_sizes; (void)n_in; (void)out_size;

    // edges + CSR (padded layout)
    k_detect_zero<<<(NN + 255) / 256, 256, 0, stream>>>((const unsigned int*)ei, eflag, deg);
    k_norm_hist<<<NE / 256, 256, 0, stream>>>(ei, eflag, srcv, dstv, deg);
    k_scan<<<1, 1024, 0, stream>>>(deg, offs, cursor);
    // prep fills srcs/dstp pad defaults BEFORE scatter writes real slots
    k_prep<<<(NN * 128 + 128 * 2048 + 64 * 1024 + 255) / 256, 256, 0, stream>>>(
        x, Xb, W1, Wt1, W2, Wt2, srcs, dstp);
    k_scatter<<<NE / 256, 256, 0, stream>>>(srcv, dstv, cursor, srcs, dstp);

    // ---- Layer 1: K=128, C=64, M=2048 ----
    k_gemm_mfma<128, 2048, 64><<<dim3((NN + 63) / 64, 2048 / 128), 256, 0, stream>>>(
        Xb, Wt1, as1, ad1, xpb, aS, aD);
    k_score_edge<<<NE_PAD / 256, 256, 0, stream>>>(aS, aD, srcs, dstp, pEh);
    k_agg_slice<64><<<(NN / 4) * 16, 256, 0, stream>>>(xpb, pEh, offs, srcs, P1);  // merged 2 passes
    k_reduce<64, 16, true><<<NN / 16, 256, 0, stream>>>(P1, b1, out, 0, z1b);

    // ---- Layer 2: K=64, C=32, M=1024 ----
    k_gemm_mfma<64, 1024, 32><<<dim3((NN + 63) / 64, 1024 / 128), 256, 0, stream>>>(
        z1b, Wt2, as2, ad2, xpb, aS, aD);
    k_score_edge<<<NE_PAD / 256, 256, 0, stream>>>(aS, aD, srcs, dstp, pEh);
    k_agg_slice<32><<<(NN / 4) * 8, 256, 0, stream>>>(xpb, pEh, offs, srcs, P2);
    k_reduce<32, 8, false><<<(NN * 8 + 255) / 256, 256, 0, stream>>>(P2, b2, out, 64, nullptr);
}